// Round 14
// baseline (448.985 us; speedup 1.0000x reference)
//
#include <hip/hip_runtime.h>
#include <hip/hip_bf16.h>

#define NN 100000
#define NE 1600000
#define EPS 1e-5f
#define NCHUNK 98   // ceil(NN/1024)
#define NB 196      // buckets of 512 dst-nodes
#define BCAP2 10240 // per-bucket capacity in staged (mean ~8163)
#define RND 4096    // edges per binning round
#define NRND 391    // ceil(NE/RND)

typedef __attribute__((ext_vector_type(8))) short short8;
typedef __attribute__((ext_vector_type(4))) float f32x4;

__device__ __forceinline__ float b2f_lo(unsigned u){ return __uint_as_float(u << 16); }
__device__ __forceinline__ float b2f_hi(unsigned u){ return __uint_as_float(u & 0xffff0000u); }
__device__ __forceinline__ float b2f_u(unsigned short u){ return __uint_as_float(((unsigned)u) << 16); }
__device__ __forceinline__ unsigned short f2b(float f){
  __hip_bfloat16 h = __float2bfloat16(f);
  return __builtin_bit_cast(unsigned short, h);
}

// ---------------- edge dtype probe (int64 vs int32) + bucket cursor init ----------------
__global__ void k_probe(const int* __restrict__ ei32, int* __restrict__ flag, int* __restrict__ gcur){
  __shared__ int cnt;
  if (threadIdx.x == 0) cnt = 0;
  __syncthreads();
  if (ei32[threadIdx.x * 2 + 1] == 0) atomicAdd(&cnt, 1);  // high words all 0 iff int64
  __syncthreads();
  if (threadIdx.x == 0) flag[0] = (cnt > 200) ? 1 : 0;
  for (int i = threadIdx.x; i < NB; i += 256) gcur[i] = i * BCAP2;
}

// ---------------- LDS-binning multisplit: edges -> bucket-contiguous staged ----------------
__global__ __launch_bounds__(1024) void k_bin(const void* __restrict__ ei, const int* __restrict__ flag,
                                              int* __restrict__ gcur, int* __restrict__ staged){
  __shared__ int hcnt[256];
  __shared__ int pref[256];
  __shared__ int bnd[200];
  __shared__ int hrun[196];
  __shared__ int gb[196];
  __shared__ int sbuf[RND];
  int t = threadIdx.x;
  int base = blockIdx.x * RND;
  bool f64 = (flag[0] != 0);
  int pay[4], bkt[4];
  #pragma unroll
  for (int k = 0; k < 4; ++k){
    int e = base + k * 1024 + t;
    if (e < NE){
      int src, dst;
      if (f64){ src = (int)((const long long*)ei)[e]; dst = (int)((const long long*)ei)[NE + e]; }
      else    { src = ((const int*)ei)[e];            dst = ((const int*)ei)[NE + e]; }
      pay[k] = (src << 9) | (dst & 511);
      bkt[k] = dst >> 9;
    } else { pay[k] = 0; bkt[k] = -1; }
  }
  if (t < 256) hcnt[t] = 0;
  __syncthreads();
  #pragma unroll
  for (int k = 0; k < 4; ++k)
    if (bkt[k] >= 0) atomicAdd(&hcnt[bkt[k]], 1);
  __syncthreads();
  if (t < 256) pref[t] = hcnt[t];
  __syncthreads();
  for (int off = 1; off < 256; off <<= 1){
    int v = 0;
    if (t < 256 && t >= off) v = pref[t - off];
    __syncthreads();
    if (t < 256) pref[t] += v;
    __syncthreads();
  }
  if (t < 196){
    int excl = pref[t] - hcnt[t];
    bnd[t] = excl;
    hrun[t] = excl;
    gb[t] = (hcnt[t] > 0) ? atomicAdd(&gcur[t], hcnt[t]) : 0;
  }
  if (t == 196) bnd[196] = 0;
  __syncthreads();
  if (t == 0) bnd[196] = pref[255];
  __syncthreads();
  #pragma unroll
  for (int k = 0; k < 4; ++k)
    if (bkt[k] >= 0){
      int lp = atomicAdd(&hrun[bkt[k]], 1);
      sbuf[lp] = pay[k];
    }
  __syncthreads();
  int total = bnd[196];
  for (int i = t; i < total; i += 1024){
    int b = 0;
    #pragma unroll
    for (int sh = 128; sh > 0; sh >>= 1)
      if (b + sh <= 196 && bnd[b + sh] <= i) b += sh;
    staged[gb[b] + (i - bnd[b])] = sbuf[i];
  }
}

// ---------------- per-bucket degree count (LDS atomics only) ----------------
__global__ __launch_bounds__(256) void k_bdeg(const int* __restrict__ staged, const int* __restrict__ gcur,
                                              int* __restrict__ deg){
  __shared__ int dcnt[512];
  int b = blockIdx.x, t = threadIdx.x;
  for (int l = t; l < 512; l += 256) dcnt[l] = 0;
  __syncthreads();
  int cnt = min(gcur[b] - b * BCAP2, BCAP2);
  const int* sp = staged + b * BCAP2;
  for (int i = t; i < cnt; i += 256)
    atomicAdd(&dcnt[sp[i] & 511], 1);
  __syncthreads();
  for (int l = t; l < 512; l += 256){
    int n = b * 512 + l;
    if (n < NN) deg[n] = dcnt[l];
  }
}

// ---------------- scans ----------------
__global__ void k_scan1(const int* __restrict__ deg, int* __restrict__ cinc, int* __restrict__ part){
  __shared__ int b[1024];
  int i = blockIdx.x * 1024 + threadIdx.x;
  int v = (i < NN) ? deg[i] : 0;
  b[threadIdx.x] = v; __syncthreads();
  for (int off = 1; off < 1024; off <<= 1){
    int t = (threadIdx.x >= off) ? b[threadIdx.x - off] : 0;
    __syncthreads();
    b[threadIdx.x] += t;
    __syncthreads();
  }
  if (i < NN) cinc[i] = b[threadIdx.x];
  if (threadIdx.x == 1023) part[blockIdx.x] = b[1023];
}

__global__ void k_scan2(int* __restrict__ part, int nchunk){
  __shared__ int b[128];
  int tid = threadIdx.x;
  int v = (tid < nchunk) ? part[tid] : 0;
  b[tid] = v; __syncthreads();
  for (int off = 1; off < 128; off <<= 1){
    int t = (tid >= off) ? b[tid - off] : 0;
    __syncthreads();
    b[tid] += t;
    __syncthreads();
  }
  if (tid < nchunk) part[tid] = b[tid] - v;   // exclusive
}

__global__ void k_scan3(const int* __restrict__ deg, const int* __restrict__ cinc,
                        const int* __restrict__ part, int* __restrict__ rowp){
  int i = blockIdx.x * 1024 + threadIdx.x;
  if (i < NN){
    rowp[i] = cinc[i] - deg[i] + part[blockIdx.x];
  }
  if (i == 0) rowp[NN] = NE;
}

// ---------------- per-bucket scatter into CSR ----------------
__global__ __launch_bounds__(256) void k_scatter2(const int* __restrict__ staged, const int* __restrict__ gcur,
                                                  const int* __restrict__ rowp, int* __restrict__ colidx){
  __shared__ int cur[512];
  int b = blockIdx.x, t = threadIdx.x;
  for (int l = t; l < 512; l += 256){
    int n = b * 512 + l;
    cur[l] = (n < NN) ? rowp[n] : 0;
  }
  __syncthreads();
  int cnt = min(gcur[b] - b * BCAP2, BCAP2);
  const int* sp = staged + b * BCAP2;
  for (int i = t; i < cnt; i += 256){
    int p = sp[i];
    int pos = atomicAdd(&cur[p & 511], 1);
    colidx[pos] = p >> 9;
  }
}

// ---------------- prep stage 1 ----------------
__global__ void k_prep_sort(const float* __restrict__ w1, const float* __restrict__ b1,
                            const float* __restrict__ g1, const float* __restrict__ be1,
                            const float* __restrict__ m1, const float* __restrict__ v1,
                            const float* __restrict__ w3, const float* __restrict__ b3,
                            const float* __restrict__ g2, const float* __restrict__ be2,
                            const float* __restrict__ m2, const float* __restrict__ v2,
                            float* __restrict__ aC, float* __restrict__ cC,
                            float* __restrict__ thrS, int* __restrict__ pos,
                            unsigned short* __restrict__ w3s, float* __restrict__ b3p){
  __shared__ float key[256];
  __shared__ int idx[256];
  int tid = threadIdx.x;
  {
    float inv = rsqrtf(v1[tid] + EPS);
    float sc = g1[tid] * inv;
    float a = w1[tid] * sc;
    float c = (b1[tid] - m1[tid]) * sc + be1[tid];
    aC[tid] = a; cC[tid] = c;
    key[tid] = (a != 0.0f) ? (-c / a) : __int_as_float(0x7f800000);
    idx[tid] = tid;
  }
  __syncthreads();
  for (int k = 2; k <= 256; k <<= 1){
    for (int j = k >> 1; j > 0; j >>= 1){
      int ixj = tid ^ j;
      if (ixj > tid){
        float k1 = key[tid], k2 = key[ixj];
        bool asc = ((tid & k) == 0);
        if ((k1 > k2) == asc){
          int i1 = idx[tid];
          key[tid] = k2; key[ixj] = k1;
          idx[tid] = idx[ixj]; idx[ixj] = i1;
        }
      }
      __syncthreads();
    }
  }
  thrS[tid] = key[tid];
  pos[idx[tid]] = tid;
  if (tid < 64){
    float i2 = rsqrtf(v2[tid] + EPS);
    b3p[tid] = (b3[tid] - m2[tid]) * i2 * g2[tid] + be2[tid];
  }
  for (int id = tid; id < 8192; id += 256){
    int cs = id >> 11, r = id & 2047;
    int kt = r >> 9;  r &= 511;
    int l = r >> 3;   int mi = r & 7;
    int krow = kt * 32 + (l >> 4) * 8 + mi;
    int col  = cs * 16 + (l & 15);
    float i2 = rsqrtf(v2[col] + EPS);
    w3s[id] = f2b(w3[krow * 64 + col] * i2 * g2[col]);
  }
}

// ---------------- prep stage 2 ----------------
__global__ void k_tab(const float* __restrict__ aC, const float* __restrict__ cC,
                      const int* __restrict__ pos, const float* __restrict__ w2,
                      const float* __restrict__ b2, unsigned short* __restrict__ tabG){
  __shared__ float ca[256], cc[256];
  int t = blockIdx.x;
  int tid = threadIdx.x;
  {
    float a = aC[tid], c = cC[tid];
    int p = pos[tid];
    bool act = (a > 0.f) ? (p < t) : ((a < 0.f) ? (p >= t) : (c > 0.f));
    ca[tid] = act ? a : 0.f;
    cc[tid] = act ? c : 0.f;
  }
  __syncthreads();
  int f = tid & 127, sel = tid >> 7;
  const float* coef = sel ? cc : ca;
  float acc = sel ? b2[f] : 0.f;
  #pragma unroll 8
  for (int j = 0; j < 256; ++j)
    acc = fmaf(coef[j], w2[j * 128 + f], acc);
  tabG[t * 256 + sel * 128 + f] = f2b(acc);
}

// ---------------- wb -> bf16 MFMA B-fragment order ----------------
__global__ void k_wbS(const float* __restrict__ wb, unsigned short* __restrict__ wbS){
  int id = blockIdx.x * 256 + threadIdx.x;
  if (id >= 64 * 6144) return;
  int j = id / 6144;
  int r = id % 6144;
  int f = r >> 9;  r &= 511;
  int l = r >> 3;  int mi = r & 7;
  int kt = f / 6, cs = f % 6;
  int i = kt * 32 + (l >> 4) * 8 + mi;
  int k = cs * 16 + (l & 15);
  wbS[id] = f2b(wb[(k * 64 + i) * 64 + j]);
}

// ---------------- scalar aggregation + interval search ----------------
__global__ void k_sagg(const float* __restrict__ x, const int* __restrict__ rowp,
                       const int* __restrict__ colidx, const float* __restrict__ thrS,
                       float4* __restrict__ info){
  __shared__ float thr[256];
  thr[threadIdx.x] = thrS[threadIdx.x];
  __syncthreads();
  int n = blockIdx.x * 256 + threadIdx.x;
  if (n >= NN) return;
  float2 xv = ((const float2*)x)[n];
  float sA = xv.y, sB = xv.x;
  int s0 = rowp[n], s1 = rowp[n + 1];
  for (int e = s0; e < s1; ++e){
    int j = colidx[e];
    float2 xj = ((const float2*)x)[j];
    sA += xj.y; sB += xj.x;
  }
  int tA = 0, tB = 0;
  #pragma unroll
  for (int sh = 128; sh > 0; sh >>= 1){
    if (tA + sh <= 256 && thr[tA + sh - 1] < sA) tA += sh;
    if (tB + sh <= 256 && thr[tB + sh - 1] < sB) tB += sh;
  }
  info[n] = make_float4(sA, sB, __uint_as_float((unsigned)tA | ((unsigned)tB << 16)), 0.f);
}

// ---------------- per-node affine eval: y[n] = A[t_n]*s_n + B[t_n] (one path) ----------------
// y row = 128 bf16 = 64 uints = 256 B. Thread per (node, feature-quad).
__global__ __launch_bounds__(256) void k_y(const float4* __restrict__ info,
                                           const unsigned* __restrict__ tabG32,
                                           unsigned* __restrict__ y, int path){
  int id = blockIdx.x * 256 + threadIdx.x;
  int n = id >> 5, q = id & 31;
  if (n >= NN) return;
  float4 inf = info[n];
  float s = path ? inf.y : inf.x;
  unsigned tt = __float_as_uint(inf.z);
  int t = path ? (int)(tt >> 16) : (int)(tt & 0xffffu);
  const unsigned* rp = tabG32 + t * 128;
  uint2 av = *(const uint2*)(rp + 2 * q);
  uint2 bv = *(const uint2*)(rp + 64 + 2 * q);
  float v0 = fmaf(s, b2f_lo(av.x), b2f_lo(bv.x));
  float v1 = fmaf(s, b2f_hi(av.x), b2f_hi(bv.x));
  float v2 = fmaf(s, b2f_lo(av.y), b2f_lo(bv.y));
  float v3 = fmaf(s, b2f_hi(av.y), b2f_hi(bv.y));
  unsigned o0 = (unsigned)f2b(v0) | ((unsigned)f2b(v1) << 16);
  unsigned o1 = (unsigned)f2b(v2) | ((unsigned)f2b(v3) << 16);
  *(uint2*)(y + (size_t)n * 64 + 2 * q) = make_uint2(o0, o1);
}

// ---------------- CSR row-sum gather: m[n] = y[n] + sum_{j in N(n)} y[j] ----------------
// Wave per node; per wave-iter 2 edges (32 lanes each, 256-B coalesced row read).
__global__ __launch_bounds__(256) void k_gather(const unsigned* __restrict__ y,
                                                const int* __restrict__ rowp,
                                                const int* __restrict__ colidx,
                                                unsigned short* __restrict__ mOut){
  int lane = threadIdx.x & 63;
  int wv = (blockIdx.x * 256 + threadIdx.x) >> 6;
  int nw = (gridDim.x * 256) >> 6;
  int h = lane >> 5, fl = lane & 31;
  for (int n = wv; n < NN; n += nw){
    int s0 = rowp[n], cnt = rowp[n + 1] - s0 + 1;  // +1 self
    float a0 = 0.f, a1 = 0.f, a2 = 0.f, a3 = 0.f;
    for (int base = 0; base < cnt; base += 2){
      int ec = base + h;
      if (ec < cnt){
        int j = (ec == 0) ? n : colidx[s0 + ec - 1];
        uint2 v = *(const uint2*)(y + (size_t)j * 64 + fl * 2);
        a0 += b2f_lo(v.x); a1 += b2f_hi(v.x);
        a2 += b2f_lo(v.y); a3 += b2f_hi(v.y);
      }
    }
    a0 += __shfl_xor(a0, 32);
    a1 += __shfl_xor(a1, 32);
    a2 += __shfl_xor(a2, 32);
    a3 += __shfl_xor(a3, 32);
    if (h == 0){
      unsigned o0 = (unsigned)f2b(a0) | ((unsigned)f2b(a1) << 16);
      unsigned o1 = (unsigned)f2b(a2) | ((unsigned)f2b(a3) << 16);
      *(uint2*)((unsigned*)(mOut + (size_t)n * 128) + fl * 2) = make_uint2(o0, o1);
    }
  }
}

// ---------------- mlp2 (MFMA) ----------------
__global__ void k_mlp2(const unsigned short* __restrict__ mA, const unsigned short* __restrict__ mB,
                       const unsigned short* __restrict__ w3s, const float* __restrict__ b3p,
                       unsigned short* __restrict__ h1, unsigned short* __restrict__ h2T){
  int lane = threadIdx.x & 63;
  int tile = (blockIdx.x * blockDim.x + threadIdx.x) >> 6;
  const int NT = 2 * NN / 16;
  if (tile >= NT) return;
  bool pB = (tile >= NN / 16);
  const unsigned short* src = pB ? (mB + (size_t)(tile - NN / 16) * 16 * 128)
                                 : (mA + (size_t)tile * 16 * 128);
  short8 afr[4];
  {
    int row = lane & 15, ko = (lane >> 4) * 8;
    #pragma unroll
    for (int kt = 0; kt < 4; ++kt)
      afr[kt] = *(const short8*)(src + row * 128 + kt * 32 + ko);
  }
  f32x4 acc[4];
  #pragma unroll
  for (int cs = 0; cs < 4; ++cs){
    f32x4 a = {0.f, 0.f, 0.f, 0.f};
    #pragma unroll
    for (int kt = 0; kt < 4; ++kt){
      short8 b = *(const short8*)(w3s + ((cs * 4 + kt) * 64 + lane) * 8);
      a = __builtin_amdgcn_mfma_f32_16x16x32_bf16(afr[kt], b, a, 0, 0, 0);
    }
    acc[cs] = a;
  }
  int col0 = lane & 15, r0 = (lane >> 4) * 4;
  if (!pB){
    int nb = tile * 16;
    #pragma unroll
    for (int cs = 0; cs < 4; ++cs){
      float bias = b3p[cs * 16 + col0];
      #pragma unroll
      for (int r = 0; r < 4; ++r){
        float v = fmaxf(acc[cs][r] + bias, 0.f);
        h1[(size_t)(nb + r0 + r) * 64 + cs * 16 + col0] = f2b(v);
      }
    }
  } else {
    int nb = (tile - NN / 16) * 16;
    #pragma unroll
    for (int cs = 0; cs < 4; ++cs){
      float bias = b3p[cs * 16 + col0];
      unsigned p0 = (unsigned)f2b(fmaxf(acc[cs][0] + bias, 0.f)) | ((unsigned)f2b(fmaxf(acc[cs][1] + bias, 0.f)) << 16);
      unsigned p1 = (unsigned)f2b(fmaxf(acc[cs][2] + bias, 0.f)) | ((unsigned)f2b(fmaxf(acc[cs][3] + bias, 0.f)) << 16);
      *(uint2*)(h2T + (size_t)(cs * 16 + col0) * NN + nb + r0) = make_uint2(p0, p1);
    }
  }
}

// ---------------- bilinear (96x64x64) + head + log_softmax ----------------
// R8 structure (2 waves, j-split, 64 rows), 12.25KB overlaid LDS, launch_bounds(128,2) (no spill).
__global__ __launch_bounds__(128, 2) void k_bil(
    const unsigned short* __restrict__ h1, const unsigned short* __restrict__ h2T,
    const unsigned short* __restrict__ wbS, const float* __restrict__ bbv,
    const float* __restrict__ w5, const float* __restrict__ b5,
    const float* __restrict__ w6, const float* __restrict__ b6,
    float* __restrict__ out){
  __shared__ float smem[3136];                 // 12544 B, all phases overlaid
  unsigned short* h2sT = (unsigned short*)smem;  // [64 j][64]: j*64 + rl*4 + rt
  int tid = threadIdx.x;
  int lane = tid & 63;
  int wv = tid >> 6;                           // 0 or 1
  int nb = blockIdx.x * 64;
  int rl = lane & 15, ko = (lane >> 4) * 8;
  for (int i = tid; i < 64 * 64; i += 128){
    int j = i >> 6, l = (i >> 2) & 15, rt = i & 3;
    int n = nb + rt * 16 + l;
    h2sT[i] = (n < NN) ? h2T[(size_t)j * NN + n] : (unsigned short)0;
  }
  float af[4][2][8];
  #pragma unroll
  for (int rt = 0; rt < 4; ++rt){
    int row = nb + rt * 16 + rl;
    #pragma unroll
    for (int kt = 0; kt < 2; ++kt){
      if (row < NN){
        uint4 rv = *(const uint4*)(h1 + (size_t)row * 64 + kt * 32 + ko);
        af[rt][kt][0] = b2f_lo(rv.x); af[rt][kt][1] = b2f_hi(rv.x);
        af[rt][kt][2] = b2f_lo(rv.y); af[rt][kt][3] = b2f_hi(rv.y);
        af[rt][kt][4] = b2f_lo(rv.z); af[rt][kt][5] = b2f_hi(rv.z);
        af[rt][kt][6] = b2f_lo(rv.w); af[rt][kt][7] = b2f_hi(rv.w);
      } else {
        #pragma unroll
        for (int e = 0; e < 8; ++e) af[rt][kt][e] = 0.f;
      }
    }
  }
  __syncthreads();
  f32x4 acc[4][6];
  #pragma unroll
  for (int rt = 0; rt < 4; ++rt)
    #pragma unroll
    for (int cs = 0; cs < 6; ++cs)
      acc[rt][cs] = (f32x4){0.f, 0.f, 0.f, 0.f};
  const unsigned short* wp = wbS + (size_t)lane * 8;
  int j0 = wv * 32, j1 = j0 + 32;
  for (int j = j0; j < j1; ++j){
    uint4 bf[2][6];
    #pragma unroll
    for (int kt = 0; kt < 2; ++kt)
      #pragma unroll
      for (int cs = 0; cs < 6; ++cs)
        bf[kt][cs] = *(const uint4*)(wp + (size_t)(j * 12 + kt * 6 + cs) * 512);
    uint2 hsv = *(const uint2*)(h2sT + j * 64 + rl * 4);
    float hsr[4];
    hsr[0] = b2f_lo(hsv.x); hsr[1] = b2f_hi(hsv.x);
    hsr[2] = b2f_lo(hsv.y); hsr[3] = b2f_hi(hsv.y);
    #pragma unroll
    for (int rt = 0; rt < 4; ++rt){
      float hs = hsr[rt];
      short8 a0, a1;
      #pragma unroll
      for (int e = 0; e < 8; ++e){
        a0[e] = (short)f2b(af[rt][0][e] * hs);
        a1[e] = (short)f2b(af[rt][1][e] * hs);
      }
      #pragma unroll
      for (int cs = 0; cs < 6; ++cs){
        acc[rt][cs] = __builtin_amdgcn_mfma_f32_16x16x32_bf16(a0, __builtin_bit_cast(short8, bf[0][cs]), acc[rt][cs], 0, 0, 0);
        acc[rt][cs] = __builtin_amdgcn_mfma_f32_16x16x32_bf16(a1, __builtin_bit_cast(short8, bf[1][cs]), acc[rt][cs], 0, 0, 0);
      }
    }
  }
  float* red = smem;
  __syncthreads();
  if (wv == 1){
    #pragma unroll
    for (int rt = 0; rt < 4; ++rt)
      #pragma unroll
      for (int cs = 0; cs < 3; ++cs){
        int col = cs * 16 + rl;
        #pragma unroll
        for (int r = 0; r < 4; ++r){
          int row = rt * 16 + (lane >> 4) * 4 + r;
          red[row * 49 + col] = acc[rt][cs][r];
        }
      }
  }
  __syncthreads();
  if (wv == 0){
    #pragma unroll
    for (int rt = 0; rt < 4; ++rt)
      #pragma unroll
      for (int cs = 0; cs < 3; ++cs){
        int col = cs * 16 + rl;
        #pragma unroll
        for (int r = 0; r < 4; ++r){
          int row = rt * 16 + (lane >> 4) * 4 + r;
          acc[rt][cs][r] += red[row * 49 + col];
        }
      }
  }
  __syncthreads();
  if (wv == 1){
    #pragma unroll
    for (int rt = 0; rt < 4; ++rt)
      #pragma unroll
      for (int cs = 3; cs < 6; ++cs){
        int col = (cs - 3) * 16 + rl;
        #pragma unroll
        for (int r = 0; r < 4; ++r){
          int row = rt * 16 + (lane >> 4) * 4 + r;
          red[row * 49 + col] = acc[rt][cs][r];
        }
      }
  }
  __syncthreads();
  if (wv == 0){
    #pragma unroll
    for (int rt = 0; rt < 4; ++rt)
      #pragma unroll
      for (int cs = 3; cs < 6; ++cs){
        int col = (cs - 3) * 16 + rl;
        #pragma unroll
        for (int r = 0; r < 4; ++r){
          int row = rt * 16 + (lane >> 4) * 4 + r;
          acc[rt][cs][r] += red[row * 49 + col];
        }
      }
  }
  __syncthreads();
  if (wv == 0){
    unsigned short* hbs = (unsigned short*)smem;   // [64][98]
    #pragma unroll
    for (int rt = 0; rt < 4; ++rt)
      #pragma unroll
      for (int cs = 0; cs < 6; ++cs){
        int col = cs * 16 + rl;
        float bias = bbv[col];
        #pragma unroll
        for (int r = 0; r < 4; ++r){
          int rowl = rt * 16 + (lane >> 4) * 4 + r;
          hbs[rowl * 98 + col] = f2b(acc[rt][cs][r] + bias);
        }
      }
    int n = nb + lane;
    if (n < NN){
      float u[6];
      #pragma unroll
      for (int q = 0; q < 6; ++q) u[q] = b5[q];
      for (int jj = 0; jj < 96; ++jj){
        float hv = b2f_u(hbs[lane * 98 + jj]);
        #pragma unroll
        for (int q = 0; q < 6; ++q) u[q] = fmaf(hv, w5[jj * 6 + q], u[q]);
      }
      #pragma unroll
      for (int q = 0; q < 6; ++q) u[q] = fmaxf(u[q], 0.f);
      float v[6];
      #pragma unroll
      for (int q = 0; q < 6; ++q){
        float a2 = b6[q];
        #pragma unroll
        for (int pp = 0; pp < 6; ++pp) a2 = fmaf(u[pp], w6[pp * 6 + q], a2);
        v[q] = a2;
      }
      float mx = v[0];
      #pragma unroll
      for (int q = 1; q < 6; ++q) mx = fmaxf(mx, v[q]);
      float se = 0.f;
      #pragma unroll
      for (int q = 0; q < 6; ++q) se += expf(v[q] - mx);
      float ls = logf(se);
      #pragma unroll
      for (int q = 0; q < 6; ++q) out[(size_t)n * 6 + q] = v[q] - mx - ls;
    }
  }
}

extern "C" void kernel_launch(void* const* d_in, const int* in_sizes, int n_in,
                              void* d_out, int out_size, void* d_ws, size_t ws_size,
                              hipStream_t stream){
  const float* x   = (const float*)d_in[0];
  const void*  ei  = d_in[1];
  const float* w1  = (const float*)d_in[2];
  const float* b1  = (const float*)d_in[3];
  const float* g1  = (const float*)d_in[4];
  const float* be1 = (const float*)d_in[5];
  const float* m1  = (const float*)d_in[6];
  const float* v1  = (const float*)d_in[7];
  const float* w2  = (const float*)d_in[8];
  const float* b2  = (const float*)d_in[9];
  const float* w3  = (const float*)d_in[10];
  const float* b3  = (const float*)d_in[11];
  const float* g2  = (const float*)d_in[12];
  const float* be2 = (const float*)d_in[13];
  const float* m2  = (const float*)d_in[14];
  const float* v2  = (const float*)d_in[15];
  const float* wb  = (const float*)d_in[16];
  const float* bb  = (const float*)d_in[17];
  const float* w5  = (const float*)d_in[18];
  const float* b5  = (const float*)d_in[19];
  const float* w6  = (const float*)d_in[20];
  const float* b6  = (const float*)d_in[21];
  float* out = (float*)d_out;

  char* ws = (char*)d_ws;
  size_t off = 0;
  auto alloc = [&](size_t bytes) -> void* {
    void* p = ws + off;
    off += (bytes + 255) & ~(size_t)255;
    return p;
  };
  int* deg      = (int*)alloc((size_t)NN * 4);
  int* rowp     = (int*)alloc((size_t)(NN + 1) * 4);
  int* cinc     = (int*)alloc((size_t)NN * 4);
  int* part     = (int*)alloc(1024 * 4);
  int* flag     = (int*)alloc(256);
  int* gcur     = (int*)alloc((size_t)NB * 4 + 256);
  int* colidx   = (int*)alloc((size_t)NE * 4);
  float4* info  = (float4*)alloc((size_t)NN * 16);
  unsigned short* tabG = (unsigned short*)alloc(257 * 256 * 2);
  float* thrS   = (float*)alloc(256 * 4);
  float* aC     = (float*)alloc(256 * 4);
  float* cC     = (float*)alloc(256 * 4);
  int* pos      = (int*)alloc(256 * 4);
  unsigned short* w3s  = (unsigned short*)alloc(8192 * 2);
  float* b3p    = (float*)alloc(64 * 4);
  unsigned short* wbS  = (unsigned short*)alloc((size_t)393216 * 2);
  unsigned short* mA   = (unsigned short*)alloc((size_t)NN * 128 * 2);
  unsigned short* mB   = (unsigned short*)alloc((size_t)NN * 128 * 2);
  unsigned short* h1   = (unsigned short*)alloc((size_t)NN * 64 * 2);
  unsigned short* h2T  = (unsigned short*)alloc((size_t)NN * 64 * 2);
  int* staged   = (int*)mA;       // 8.03 MB aliases mA; consumed before gathers write mA
  unsigned* y   = (unsigned*)h1;  // 25.6 MB aliases h1+h2T; dead before k_mlp2 writes them

  k_probe<<<1, 256, 0, stream>>>((const int*)ei, flag, gcur);
  k_bin<<<NRND, 1024, 0, stream>>>(ei, flag, gcur, staged);
  k_bdeg<<<NB, 256, 0, stream>>>(staged, gcur, deg);
  k_scan1<<<NCHUNK, 1024, 0, stream>>>(deg, cinc, part);
  k_scan2<<<1, 128, 0, stream>>>(part, NCHUNK);
  k_scan3<<<NCHUNK, 1024, 0, stream>>>(deg, cinc, part, rowp);
  k_scatter2<<<NB, 256, 0, stream>>>(staged, gcur, rowp, colidx);
  k_prep_sort<<<1, 256, 0, stream>>>(w1, b1, g1, be1, m1, v1, w3, b3, g2, be2, m2, v2,
                                     aC, cC, thrS, pos, w3s, b3p);
  k_tab<<<257, 256, 0, stream>>>(aC, cC, pos, w2, b2, tabG);
  k_wbS<<<(64 * 6144 + 255) / 256, 256, 0, stream>>>(wb, wbS);
  k_sagg<<<(NN + 255) / 256, 256, 0, stream>>>(x, rowp, colidx, thrS, info);
  // path A: y = A-path per-node affine, then CSR row-sum into mA
  k_y<<<(NN * 32 + 255) / 256, 256, 0, stream>>>(info, (const unsigned*)tabG, y, 0);
  k_gather<<<2048, 256, 0, stream>>>(y, rowp, colidx, mA);
  // path B
  k_y<<<(NN * 32 + 255) / 256, 256, 0, stream>>>(info, (const unsigned*)tabG, y, 1);
  k_gather<<<2048, 256, 0, stream>>>(y, rowp, colidx, mB);
  k_mlp2<<<(2 * NN / 16 + 3) / 4, 256, 0, stream>>>(mA, mB, w3s, b3p, h1, h2T);
  k_bil<<<(NN + 63) / 64, 128, 0, stream>>>(h1, h2T, wbS, bb, w5, b5, w6, b6, out);
}

// Round 15
// 325.075 us; speedup vs baseline: 1.3812x; 1.3812x over previous
//
#include <hip/hip_runtime.h>
#include <hip/hip_bf16.h>

#define NN 100000
#define NE 1600000
#define EPS 1e-5f
#define NCHUNK 98   // ceil(NN/1024)
#define NB 196      // buckets of 512 dst-nodes
#define BCAP2 10240 // per-bucket capacity in staged (mean ~8163)
#define RND 4096    // edges per binning round
#define NRND 391    // ceil(NE/RND)

typedef __attribute__((ext_vector_type(8))) short short8;
typedef __attribute__((ext_vector_type(4))) float f32x4;

__device__ __forceinline__ float b2f_lo(unsigned u){ return __uint_as_float(u << 16); }
__device__ __forceinline__ float b2f_hi(unsigned u){ return __uint_as_float(u & 0xffff0000u); }
__device__ __forceinline__ float b2f_u(unsigned short u){ return __uint_as_float(((unsigned)u) << 16); }
__device__ __forceinline__ unsigned short f2b(float f){
  __hip_bfloat16 h = __float2bfloat16(f);
  return __builtin_bit_cast(unsigned short, h);
}

// ---------------- edge dtype probe (int64 vs int32) + bucket cursor init ----------------
__global__ void k_probe(const int* __restrict__ ei32, int* __restrict__ flag, int* __restrict__ gcur){
  __shared__ int cnt;
  if (threadIdx.x == 0) cnt = 0;
  __syncthreads();
  if (ei32[threadIdx.x * 2 + 1] == 0) atomicAdd(&cnt, 1);  // high words all 0 iff int64
  __syncthreads();
  if (threadIdx.x == 0) flag[0] = (cnt > 200) ? 1 : 0;
  for (int i = threadIdx.x; i < NB; i += 256) gcur[i] = i * BCAP2;
}

// ---------------- LDS-binning multisplit: edges -> bucket-contiguous staged ----------------
__global__ __launch_bounds__(1024) void k_bin(const void* __restrict__ ei, const int* __restrict__ flag,
                                              int* __restrict__ gcur, int* __restrict__ staged){
  __shared__ int hcnt[256];
  __shared__ int pref[256];
  __shared__ int bnd[200];
  __shared__ int hrun[196];
  __shared__ int gb[196];
  __shared__ int sbuf[RND];
  int t = threadIdx.x;
  int base = blockIdx.x * RND;
  bool f64 = (flag[0] != 0);
  int pay[4], bkt[4];
  #pragma unroll
  for (int k = 0; k < 4; ++k){
    int e = base + k * 1024 + t;
    if (e < NE){
      int src, dst;
      if (f64){ src = (int)((const long long*)ei)[e]; dst = (int)((const long long*)ei)[NE + e]; }
      else    { src = ((const int*)ei)[e];            dst = ((const int*)ei)[NE + e]; }
      pay[k] = (src << 9) | (dst & 511);
      bkt[k] = dst >> 9;
    } else { pay[k] = 0; bkt[k] = -1; }
  }
  if (t < 256) hcnt[t] = 0;
  __syncthreads();
  #pragma unroll
  for (int k = 0; k < 4; ++k)
    if (bkt[k] >= 0) atomicAdd(&hcnt[bkt[k]], 1);
  __syncthreads();
  if (t < 256) pref[t] = hcnt[t];
  __syncthreads();
  for (int off = 1; off < 256; off <<= 1){
    int v = 0;
    if (t < 256 && t >= off) v = pref[t - off];
    __syncthreads();
    if (t < 256) pref[t] += v;
    __syncthreads();
  }
  if (t < 196){
    int excl = pref[t] - hcnt[t];
    bnd[t] = excl;
    hrun[t] = excl;
    gb[t] = (hcnt[t] > 0) ? atomicAdd(&gcur[t], hcnt[t]) : 0;
  }
  if (t == 196) bnd[196] = 0;
  __syncthreads();
  if (t == 0) bnd[196] = pref[255];
  __syncthreads();
  #pragma unroll
  for (int k = 0; k < 4; ++k)
    if (bkt[k] >= 0){
      int lp = atomicAdd(&hrun[bkt[k]], 1);
      sbuf[lp] = pay[k];
    }
  __syncthreads();
  int total = bnd[196];
  for (int i = t; i < total; i += 1024){
    int b = 0;
    #pragma unroll
    for (int sh = 128; sh > 0; sh >>= 1)
      if (b + sh <= 196 && bnd[b + sh] <= i) b += sh;
    staged[gb[b] + (i - bnd[b])] = sbuf[i];
  }
}

// ---------------- per-bucket degree count (LDS atomics only) ----------------
__global__ __launch_bounds__(256) void k_bdeg(const int* __restrict__ staged, const int* __restrict__ gcur,
                                              int* __restrict__ deg){
  __shared__ int dcnt[512];
  int b = blockIdx.x, t = threadIdx.x;
  for (int l = t; l < 512; l += 256) dcnt[l] = 0;
  __syncthreads();
  int cnt = min(gcur[b] - b * BCAP2, BCAP2);
  const int* sp = staged + b * BCAP2;
  for (int i = t; i < cnt; i += 256)
    atomicAdd(&dcnt[sp[i] & 511], 1);
  __syncthreads();
  for (int l = t; l < 512; l += 256){
    int n = b * 512 + l;
    if (n < NN) deg[n] = dcnt[l];
  }
}

// ---------------- scans ----------------
__global__ void k_scan1(const int* __restrict__ deg, int* __restrict__ cinc, int* __restrict__ part){
  __shared__ int b[1024];
  int i = blockIdx.x * 1024 + threadIdx.x;
  int v = (i < NN) ? deg[i] : 0;
  b[threadIdx.x] = v; __syncthreads();
  for (int off = 1; off < 1024; off <<= 1){
    int t = (threadIdx.x >= off) ? b[threadIdx.x - off] : 0;
    __syncthreads();
    b[threadIdx.x] += t;
    __syncthreads();
  }
  if (i < NN) cinc[i] = b[threadIdx.x];
  if (threadIdx.x == 1023) part[blockIdx.x] = b[1023];
}

__global__ void k_scan2(int* __restrict__ part, int nchunk){
  __shared__ int b[128];
  int tid = threadIdx.x;
  int v = (tid < nchunk) ? part[tid] : 0;
  b[tid] = v; __syncthreads();
  for (int off = 1; off < 128; off <<= 1){
    int t = (tid >= off) ? b[tid - off] : 0;
    __syncthreads();
    b[tid] += t;
    __syncthreads();
  }
  if (tid < nchunk) part[tid] = b[tid] - v;   // exclusive
}

__global__ void k_scan3(const int* __restrict__ deg, const int* __restrict__ cinc,
                        const int* __restrict__ part, int* __restrict__ rowp){
  int i = blockIdx.x * 1024 + threadIdx.x;
  if (i < NN){
    rowp[i] = cinc[i] - deg[i] + part[blockIdx.x];
  }
  if (i == 0) rowp[NN] = NE;
}

// ---------------- per-bucket scatter into CSR ----------------
__global__ __launch_bounds__(256) void k_scatter2(const int* __restrict__ staged, const int* __restrict__ gcur,
                                                  const int* __restrict__ rowp, int* __restrict__ colidx){
  __shared__ int cur[512];
  int b = blockIdx.x, t = threadIdx.x;
  for (int l = t; l < 512; l += 256){
    int n = b * 512 + l;
    cur[l] = (n < NN) ? rowp[n] : 0;
  }
  __syncthreads();
  int cnt = min(gcur[b] - b * BCAP2, BCAP2);
  const int* sp = staged + b * BCAP2;
  for (int i = t; i < cnt; i += 256){
    int p = sp[i];
    int pos = atomicAdd(&cur[p & 511], 1);
    colidx[pos] = p >> 9;
  }
}

// ---------------- prep stage 1 ----------------
__global__ void k_prep_sort(const float* __restrict__ w1, const float* __restrict__ b1,
                            const float* __restrict__ g1, const float* __restrict__ be1,
                            const float* __restrict__ m1, const float* __restrict__ v1,
                            const float* __restrict__ w3, const float* __restrict__ b3,
                            const float* __restrict__ g2, const float* __restrict__ be2,
                            const float* __restrict__ m2, const float* __restrict__ v2,
                            float* __restrict__ aC, float* __restrict__ cC,
                            float* __restrict__ thrS, int* __restrict__ pos,
                            unsigned short* __restrict__ w3s, float* __restrict__ b3p){
  __shared__ float key[256];
  __shared__ int idx[256];
  int tid = threadIdx.x;
  {
    float inv = rsqrtf(v1[tid] + EPS);
    float sc = g1[tid] * inv;
    float a = w1[tid] * sc;
    float c = (b1[tid] - m1[tid]) * sc + be1[tid];
    aC[tid] = a; cC[tid] = c;
    key[tid] = (a != 0.0f) ? (-c / a) : __int_as_float(0x7f800000);
    idx[tid] = tid;
  }
  __syncthreads();
  for (int k = 2; k <= 256; k <<= 1){
    for (int j = k >> 1; j > 0; j >>= 1){
      int ixj = tid ^ j;
      if (ixj > tid){
        float k1 = key[tid], k2 = key[ixj];
        bool asc = ((tid & k) == 0);
        if ((k1 > k2) == asc){
          int i1 = idx[tid];
          key[tid] = k2; key[ixj] = k1;
          idx[tid] = idx[ixj]; idx[ixj] = i1;
        }
      }
      __syncthreads();
    }
  }
  thrS[tid] = key[tid];
  pos[idx[tid]] = tid;
  if (tid < 64){
    float i2 = rsqrtf(v2[tid] + EPS);
    b3p[tid] = (b3[tid] - m2[tid]) * i2 * g2[tid] + be2[tid];
  }
  for (int id = tid; id < 8192; id += 256){
    int cs = id >> 11, r = id & 2047;
    int kt = r >> 9;  r &= 511;
    int l = r >> 3;   int mi = r & 7;
    int krow = kt * 32 + (l >> 4) * 8 + mi;
    int col  = cs * 16 + (l & 15);
    float i2 = rsqrtf(v2[col] + EPS);
    w3s[id] = f2b(w3[krow * 64 + col] * i2 * g2[col]);
  }
}

// ---------------- prep stage 2 ----------------
__global__ void k_tab(const float* __restrict__ aC, const float* __restrict__ cC,
                      const int* __restrict__ pos, const float* __restrict__ w2,
                      const float* __restrict__ b2, unsigned short* __restrict__ tabG){
  __shared__ float ca[256], cc[256];
  int t = blockIdx.x;
  int tid = threadIdx.x;
  {
    float a = aC[tid], c = cC[tid];
    int p = pos[tid];
    bool act = (a > 0.f) ? (p < t) : ((a < 0.f) ? (p >= t) : (c > 0.f));
    ca[tid] = act ? a : 0.f;
    cc[tid] = act ? c : 0.f;
  }
  __syncthreads();
  int f = tid & 127, sel = tid >> 7;
  const float* coef = sel ? cc : ca;
  float acc = sel ? b2[f] : 0.f;
  #pragma unroll 8
  for (int j = 0; j < 256; ++j)
    acc = fmaf(coef[j], w2[j * 128 + f], acc);
  tabG[t * 256 + sel * 128 + f] = f2b(acc);
}

// ---------------- wb -> bf16 MFMA B-fragment order ----------------
__global__ void k_wbS(const float* __restrict__ wb, unsigned short* __restrict__ wbS){
  int id = blockIdx.x * 256 + threadIdx.x;
  if (id >= 64 * 6144) return;
  int j = id / 6144;
  int r = id % 6144;
  int f = r >> 9;  r &= 511;
  int l = r >> 3;  int mi = r & 7;
  int kt = f / 6, cs = f % 6;
  int i = kt * 32 + (l >> 4) * 8 + mi;
  int k = cs * 16 + (l & 15);
  wbS[id] = f2b(wb[(k * 64 + i) * 64 + j]);
}

// ---------------- scalar aggregation + interval search ----------------
__global__ void k_sagg(const float* __restrict__ x, const int* __restrict__ rowp,
                       const int* __restrict__ colidx, const float* __restrict__ thrS,
                       float4* __restrict__ info){
  __shared__ float thr[256];
  thr[threadIdx.x] = thrS[threadIdx.x];
  __syncthreads();
  int n = blockIdx.x * 256 + threadIdx.x;
  if (n >= NN) return;
  float2 xv = ((const float2*)x)[n];
  float sA = xv.y, sB = xv.x;
  int s0 = rowp[n], s1 = rowp[n + 1];
  for (int e = s0; e < s1; ++e){
    int j = colidx[e];
    float2 xj = ((const float2*)x)[j];
    sA += xj.y; sB += xj.x;
  }
  int tA = 0, tB = 0;
  #pragma unroll
  for (int sh = 128; sh > 0; sh >>= 1){
    if (tA + sh <= 256 && thr[tA + sh - 1] < sA) tA += sh;
    if (tB + sh <= 256 && thr[tB + sh - 1] < sB) tB += sh;
  }
  info[n] = make_float4(sA, sB, __uint_as_float((unsigned)tA | ((unsigned)tB << 16)), 0.f);
}

// ---------------- heavy aggregation via LDS table (cross-node prefetch pipeline) ----------------
__global__ __launch_bounds__(1024) void k_agg(
    const float4* __restrict__ info, const int* __restrict__ rowp,
    const int* __restrict__ colidx, const unsigned short* __restrict__ tabG,
    unsigned short* __restrict__ mA, unsigned short* __restrict__ mB){
  extern __shared__ unsigned tab32[];
  for (int i = threadIdx.x; i < 257 * 128; i += 1024)
    tab32[i] = ((const unsigned*)tabG)[i];
  __syncthreads();
  int lane = threadIdx.x & 63;
  int wv = (blockIdx.x * 1024 + threadIdx.x) >> 6;
  int nw = (gridDim.x * 1024) >> 6;
  int p  = lane >> 5;
  int fq = lane & 31;
  int foff = fq << 3;          // byte offset of this lane's uint2 within the A half-row
  int boff = 256 + foff;       // B half-row starts at word 64 = byte 256

  int n = wv;
  if (n >= NN) return;
  int s0 = rowp[n], s1 = rowp[n + 1];
  float4 inf;
  {
    int cnt = s1 - s0 + 1;
    inf = make_float4(0, 0, 0, 0);
    if (lane < cnt) inf = info[(lane == 0) ? n : colidx[s0 + lane - 1]];
  }
  while (true){
    int cnt = s1 - s0 + 1;
    int nnx = n + nw;
    float4 infc = inf;           // this node's chunk-0 gather (already in flight/complete)
    int s0c = s0;
    int ns0 = 0, ns1 = 0;
    if (nnx < NN){
      ns0 = rowp[nnx]; ns1 = rowp[nnx + 1];
      int ncnt = ns1 - ns0 + 1;
      inf = make_float4(0, 0, 0, 0);
      if (lane < ncnt) inf = info[(lane == 0) ? nnx : colidx[ns0 + lane - 1]];
    }
    float a0 = 0.f, a1 = 0.f, a2 = 0.f, a3 = 0.f;
    for (int base = 0; base < cnt; base += 64){
      if (base > 0){
        infc = make_float4(0, 0, 0, 0);
        int nb = base + lane;
        if (nb < cnt) infc = info[colidx[s0c + nb - 1]];
      }
      int m = min(cnt - base, 64);
      for (int q = 0; q < m; ++q){
        float sA = __shfl(infc.x, q);
        float sB = __shfl(infc.y, q);
        unsigned tt = __float_as_uint(__shfl(infc.z, q));
        float s = p ? sB : sA;
        int   t = p ? (int)(tt >> 16) : (int)(tt & 0xffffu);
        const char* rp = (const char*)tab32 + t * 512;
        uint2 av = *(const uint2*)(rp + foff);
        uint2 bv = *(const uint2*)(rp + boff);
        a0 += fmaf(s, b2f_lo(av.x), b2f_lo(bv.x));
        a1 += fmaf(s, b2f_hi(av.x), b2f_hi(bv.x));
        a2 += fmaf(s, b2f_lo(av.y), b2f_lo(bv.y));
        a3 += fmaf(s, b2f_hi(av.y), b2f_hi(bv.y));
      }
    }
    unsigned short* dst = (p ? mB : mA) + (size_t)n * 128 + fq * 4;
    unsigned o0 = (unsigned)f2b(a0) | ((unsigned)f2b(a1) << 16);
    unsigned o1 = (unsigned)f2b(a2) | ((unsigned)f2b(a3) << 16);
    *((uint2*)dst) = make_uint2(o0, o1);
    if (nnx >= NN) break;
    n = nnx; s0 = ns0; s1 = ns1;
  }
}

// ---------------- mlp2 (MFMA) ----------------
__global__ void k_mlp2(const unsigned short* __restrict__ mA, const unsigned short* __restrict__ mB,
                       const unsigned short* __restrict__ w3s, const float* __restrict__ b3p,
                       unsigned short* __restrict__ h1, unsigned short* __restrict__ h2T){
  int lane = threadIdx.x & 63;
  int tile = (blockIdx.x * blockDim.x + threadIdx.x) >> 6;
  const int NT = 2 * NN / 16;
  if (tile >= NT) return;
  bool pB = (tile >= NN / 16);
  const unsigned short* src = pB ? (mB + (size_t)(tile - NN / 16) * 16 * 128)
                                 : (mA + (size_t)tile * 16 * 128);
  short8 afr[4];
  {
    int row = lane & 15, ko = (lane >> 4) * 8;
    #pragma unroll
    for (int kt = 0; kt < 4; ++kt)
      afr[kt] = *(const short8*)(src + row * 128 + kt * 32 + ko);
  }
  f32x4 acc[4];
  #pragma unroll
  for (int cs = 0; cs < 4; ++cs){
    f32x4 a = {0.f, 0.f, 0.f, 0.f};
    #pragma unroll
    for (int kt = 0; kt < 4; ++kt){
      short8 b = *(const short8*)(w3s + ((cs * 4 + kt) * 64 + lane) * 8);
      a = __builtin_amdgcn_mfma_f32_16x16x32_bf16(afr[kt], b, a, 0, 0, 0);
    }
    acc[cs] = a;
  }
  int col0 = lane & 15, r0 = (lane >> 4) * 4;
  if (!pB){
    int nb = tile * 16;
    #pragma unroll
    for (int cs = 0; cs < 4; ++cs){
      float bias = b3p[cs * 16 + col0];
      #pragma unroll
      for (int r = 0; r < 4; ++r){
        float v = fmaxf(acc[cs][r] + bias, 0.f);
        h1[(size_t)(nb + r0 + r) * 64 + cs * 16 + col0] = f2b(v);
      }
    }
  } else {
    int nb = (tile - NN / 16) * 16;
    #pragma unroll
    for (int cs = 0; cs < 4; ++cs){
      float bias = b3p[cs * 16 + col0];
      unsigned p0 = (unsigned)f2b(fmaxf(acc[cs][0] + bias, 0.f)) | ((unsigned)f2b(fmaxf(acc[cs][1] + bias, 0.f)) << 16);
      unsigned p1 = (unsigned)f2b(fmaxf(acc[cs][2] + bias, 0.f)) | ((unsigned)f2b(fmaxf(acc[cs][3] + bias, 0.f)) << 16);
      *(uint2*)(h2T + (size_t)(cs * 16 + col0) * NN + nb + r0) = make_uint2(p0, p1);
    }
  }
}

// ---------------- bilinear (96x64x64) + head + log_softmax ----------------
// R8 structure (2 waves, j-split, 64 rows), 12.25KB overlaid LDS, launch_bounds(128,2) (no spill).
__global__ __launch_bounds__(128, 2) void k_bil(
    const unsigned short* __restrict__ h1, const unsigned short* __restrict__ h2T,
    const unsigned short* __restrict__ wbS, const float* __restrict__ bbv,
    const float* __restrict__ w5, const float* __restrict__ b5,
    const float* __restrict__ w6, const float* __restrict__ b6,
    float* __restrict__ out){
  __shared__ float smem[3136];                 // 12544 B, all phases overlaid
  unsigned short* h2sT = (unsigned short*)smem;  // [64 j][64]: j*64 + rl*4 + rt
  int tid = threadIdx.x;
  int lane = tid & 63;
  int wv = tid >> 6;                           // 0 or 1
  int nb = blockIdx.x * 64;
  int rl = lane & 15, ko = (lane >> 4) * 8;
  for (int i = tid; i < 64 * 64; i += 128){
    int j = i >> 6, l = (i >> 2) & 15, rt = i & 3;
    int n = nb + rt * 16 + l;
    h2sT[i] = (n < NN) ? h2T[(size_t)j * NN + n] : (unsigned short)0;
  }
  float af[4][2][8];
  #pragma unroll
  for (int rt = 0; rt < 4; ++rt){
    int row = nb + rt * 16 + rl;
    #pragma unroll
    for (int kt = 0; kt < 2; ++kt){
      if (row < NN){
        uint4 rv = *(const uint4*)(h1 + (size_t)row * 64 + kt * 32 + ko);
        af[rt][kt][0] = b2f_lo(rv.x); af[rt][kt][1] = b2f_hi(rv.x);
        af[rt][kt][2] = b2f_lo(rv.y); af[rt][kt][3] = b2f_hi(rv.y);
        af[rt][kt][4] = b2f_lo(rv.z); af[rt][kt][5] = b2f_hi(rv.z);
        af[rt][kt][6] = b2f_lo(rv.w); af[rt][kt][7] = b2f_hi(rv.w);
      } else {
        #pragma unroll
        for (int e = 0; e < 8; ++e) af[rt][kt][e] = 0.f;
      }
    }
  }
  __syncthreads();
  f32x4 acc[4][6];
  #pragma unroll
  for (int rt = 0; rt < 4; ++rt)
    #pragma unroll
    for (int cs = 0; cs < 6; ++cs)
      acc[rt][cs] = (f32x4){0.f, 0.f, 0.f, 0.f};
  const unsigned short* wp = wbS + (size_t)lane * 8;
  int j0 = wv * 32, j1 = j0 + 32;
  for (int j = j0; j < j1; ++j){
    uint4 bf[2][6];
    #pragma unroll
    for (int kt = 0; kt < 2; ++kt)
      #pragma unroll
      for (int cs = 0; cs < 6; ++cs)
        bf[kt][cs] = *(const uint4*)(wp + (size_t)(j * 12 + kt * 6 + cs) * 512);
    uint2 hsv = *(const uint2*)(h2sT + j * 64 + rl * 4);
    float hsr[4];
    hsr[0] = b2f_lo(hsv.x); hsr[1] = b2f_hi(hsv.x);
    hsr[2] = b2f_lo(hsv.y); hsr[3] = b2f_hi(hsv.y);
    #pragma unroll
    for (int rt = 0; rt < 4; ++rt){
      float hs = hsr[rt];
      short8 a0, a1;
      #pragma unroll
      for (int e = 0; e < 8; ++e){
        a0[e] = (short)f2b(af[rt][0][e] * hs);
        a1[e] = (short)f2b(af[rt][1][e] * hs);
      }
      #pragma unroll
      for (int cs = 0; cs < 6; ++cs){
        acc[rt][cs] = __builtin_amdgcn_mfma_f32_16x16x32_bf16(a0, __builtin_bit_cast(short8, bf[0][cs]), acc[rt][cs], 0, 0, 0);
        acc[rt][cs] = __builtin_amdgcn_mfma_f32_16x16x32_bf16(a1, __builtin_bit_cast(short8, bf[1][cs]), acc[rt][cs], 0, 0, 0);
      }
    }
  }
  float* red = smem;
  __syncthreads();
  if (wv == 1){
    #pragma unroll
    for (int rt = 0; rt < 4; ++rt)
      #pragma unroll
      for (int cs = 0; cs < 3; ++cs){
        int col = cs * 16 + rl;
        #pragma unroll
        for (int r = 0; r < 4; ++r){
          int row = rt * 16 + (lane >> 4) * 4 + r;
          red[row * 49 + col] = acc[rt][cs][r];
        }
      }
  }
  __syncthreads();
  if (wv == 0){
    #pragma unroll
    for (int rt = 0; rt < 4; ++rt)
      #pragma unroll
      for (int cs = 0; cs < 3; ++cs){
        int col = cs * 16 + rl;
        #pragma unroll
        for (int r = 0; r < 4; ++r){
          int row = rt * 16 + (lane >> 4) * 4 + r;
          acc[rt][cs][r] += red[row * 49 + col];
        }
      }
  }
  __syncthreads();
  if (wv == 1){
    #pragma unroll
    for (int rt = 0; rt < 4; ++rt)
      #pragma unroll
      for (int cs = 3; cs < 6; ++cs){
        int col = (cs - 3) * 16 + rl;
        #pragma unroll
        for (int r = 0; r < 4; ++r){
          int row = rt * 16 + (lane >> 4) * 4 + r;
          red[row * 49 + col] = acc[rt][cs][r];
        }
      }
  }
  __syncthreads();
  if (wv == 0){
    #pragma unroll
    for (int rt = 0; rt < 4; ++rt)
      #pragma unroll
      for (int cs = 3; cs < 6; ++cs){
        int col = (cs - 3) * 16 + rl;
        #pragma unroll
        for (int r = 0; r < 4; ++r){
          int row = rt * 16 + (lane >> 4) * 4 + r;
          acc[rt][cs][r] += red[row * 49 + col];
        }
      }
  }
  __syncthreads();
  if (wv == 0){
    unsigned short* hbs = (unsigned short*)smem;   // [64][98]
    #pragma unroll
    for (int rt = 0; rt < 4; ++rt)
      #pragma unroll
      for (int cs = 0; cs < 6; ++cs){
        int col = cs * 16 + rl;
        float bias = bbv[col];
        #pragma unroll
        for (int r = 0; r < 4; ++r){
          int rowl = rt * 16 + (lane >> 4) * 4 + r;
          hbs[rowl * 98 + col] = f2b(acc[rt][cs][r] + bias);
        }
      }
    int n = nb + lane;
    if (n < NN){
      float u[6];
      #pragma unroll
      for (int q = 0; q < 6; ++q) u[q] = b5[q];
      for (int jj = 0; jj < 96; ++jj){
        float hv = b2f_u(hbs[lane * 98 + jj]);
        #pragma unroll
        for (int q = 0; q < 6; ++q) u[q] = fmaf(hv, w5[jj * 6 + q], u[q]);
      }
      #pragma unroll
      for (int q = 0; q < 6; ++q) u[q] = fmaxf(u[q], 0.f);
      float v[6];
      #pragma unroll
      for (int q = 0; q < 6; ++q){
        float a2 = b6[q];
        #pragma unroll
        for (int pp = 0; pp < 6; ++pp) a2 = fmaf(u[pp], w6[pp * 6 + q], a2);
        v[q] = a2;
      }
      float mx = v[0];
      #pragma unroll
      for (int q = 1; q < 6; ++q) mx = fmaxf(mx, v[q]);
      float se = 0.f;
      #pragma unroll
      for (int q = 0; q < 6; ++q) se += expf(v[q] - mx);
      float ls = logf(se);
      #pragma unroll
      for (int q = 0; q < 6; ++q) out[(size_t)n * 6 + q] = v[q] - mx - ls;
    }
  }
}

extern "C" void kernel_launch(void* const* d_in, const int* in_sizes, int n_in,
                              void* d_out, int out_size, void* d_ws, size_t ws_size,
                              hipStream_t stream){
  const float* x   = (const float*)d_in[0];
  const void*  ei  = d_in[1];
  const float* w1  = (const float*)d_in[2];
  const float* b1  = (const float*)d_in[3];
  const float* g1  = (const float*)d_in[4];
  const float* be1 = (const float*)d_in[5];
  const float* m1  = (const float*)d_in[6];
  const float* v1  = (const float*)d_in[7];
  const float* w2  = (const float*)d_in[8];
  const float* b2  = (const float*)d_in[9];
  const float* w3  = (const float*)d_in[10];
  const float* b3  = (const float*)d_in[11];
  const float* g2  = (const float*)d_in[12];
  const float* be2 = (const float*)d_in[13];
  const float* m2  = (const float*)d_in[14];
  const float* v2  = (const float*)d_in[15];
  const float* wb  = (const float*)d_in[16];
  const float* bb  = (const float*)d_in[17];
  const float* w5  = (const float*)d_in[18];
  const float* b5  = (const float*)d_in[19];
  const float* w6  = (const float*)d_in[20];
  const float* b6  = (const float*)d_in[21];
  float* out = (float*)d_out;

  char* ws = (char*)d_ws;
  size_t off = 0;
  auto alloc = [&](size_t bytes) -> void* {
    void* p = ws + off;
    off += (bytes + 255) & ~(size_t)255;
    return p;
  };
  int* deg      = (int*)alloc((size_t)NN * 4);
  int* rowp     = (int*)alloc((size_t)(NN + 1) * 4);
  int* cinc     = (int*)alloc((size_t)NN * 4);
  int* part     = (int*)alloc(1024 * 4);
  int* flag     = (int*)alloc(256);
  int* gcur     = (int*)alloc((size_t)NB * 4 + 256);
  int* colidx   = (int*)alloc((size_t)NE * 4);
  float4* info  = (float4*)alloc((size_t)NN * 16);
  unsigned short* tabG = (unsigned short*)alloc(257 * 256 * 2);
  float* thrS   = (float*)alloc(256 * 4);
  float* aC     = (float*)alloc(256 * 4);
  float* cC     = (float*)alloc(256 * 4);
  int* pos      = (int*)alloc(256 * 4);
  unsigned short* w3s  = (unsigned short*)alloc(8192 * 2);
  float* b3p    = (float*)alloc(64 * 4);
  unsigned short* wbS  = (unsigned short*)alloc((size_t)393216 * 2);
  unsigned short* mA   = (unsigned short*)alloc((size_t)NN * 128 * 2);
  unsigned short* mB   = (unsigned short*)alloc((size_t)NN * 128 * 2);
  unsigned short* h1   = (unsigned short*)alloc((size_t)NN * 64 * 2);
  unsigned short* h2T  = (unsigned short*)alloc((size_t)NN * 64 * 2);
  int* staged   = (int*)mA;   // 8.03 MB aliases mA; consumed before k_agg writes mA

  k_probe<<<1, 256, 0, stream>>>((const int*)ei, flag, gcur);
  k_bin<<<NRND, 1024, 0, stream>>>(ei, flag, gcur, staged);
  k_bdeg<<<NB, 256, 0, stream>>>(staged, gcur, deg);
  k_scan1<<<NCHUNK, 1024, 0, stream>>>(deg, cinc, part);
  k_scan2<<<1, 128, 0, stream>>>(part, NCHUNK);
  k_scan3<<<NCHUNK, 1024, 0, stream>>>(deg, cinc, part, rowp);
  k_scatter2<<<NB, 256, 0, stream>>>(staged, gcur, rowp, colidx);
  k_prep_sort<<<1, 256, 0, stream>>>(w1, b1, g1, be1, m1, v1, w3, b3, g2, be2, m2, v2,
                                     aC, cC, thrS, pos, w3s, b3p);
  k_tab<<<257, 256, 0, stream>>>(aC, cC, pos, w2, b2, tabG);
  k_wbS<<<(64 * 6144 + 255) / 256, 256, 0, stream>>>(wb, wbS);
  k_sagg<<<(NN + 255) / 256, 256, 0, stream>>>(x, rowp, colidx, thrS, info);
  hipFuncSetAttribute((const void*)k_agg, hipFuncAttributeMaxDynamicSharedMemorySize, 257 * 128 * 4);
  k_agg<<<256, 1024, 257 * 128 * 4, stream>>>(info, rowp, colidx, tabG, mA, mB);
  k_mlp2<<<(2 * NN / 16 + 3) / 4, 256, 0, stream>>>(mA, mB, w3s, b3p, h1, h2T);
  k_bil<<<(NN + 63) / 64, 128, 0, stream>>>(h1, h2T, wbS, bb, w5, b5, w6, b6, out);
}

// Round 16
// 321.882 us; speedup vs baseline: 1.3949x; 1.0099x over previous
//
#include <hip/hip_runtime.h>
#include <hip/hip_bf16.h>

#define NN 100000
#define NE 1600000
#define EPS 1e-5f
#define NCHUNK 98   // ceil(NN/1024)
#define NB 196      // buckets of 512 dst-nodes
#define BCAP2 10240 // per-bucket capacity in staged (mean ~8163)
#define RND 4096    // edges per binning round
#define NRND 391    // ceil(NE/RND)

typedef __attribute__((ext_vector_type(8))) short short8;
typedef __attribute__((ext_vector_type(4))) float f32x4;

__device__ __forceinline__ float b2f_lo(unsigned u){ return __uint_as_float(u << 16); }
__device__ __forceinline__ float b2f_hi(unsigned u){ return __uint_as_float(u & 0xffff0000u); }
__device__ __forceinline__ float b2f_u(unsigned short u){ return __uint_as_float(((unsigned)u) << 16); }
__device__ __forceinline__ unsigned short f2b(float f){
  __hip_bfloat16 h = __float2bfloat16(f);
  return __builtin_bit_cast(unsigned short, h);
}

// ---------------- edge dtype probe (int64 vs int32) + bucket cursor init ----------------
__global__ void k_probe(const int* __restrict__ ei32, int* __restrict__ flag, int* __restrict__ gcur){
  __shared__ int cnt;
  if (threadIdx.x == 0) cnt = 0;
  __syncthreads();
  if (ei32[threadIdx.x * 2 + 1] == 0) atomicAdd(&cnt, 1);  // high words all 0 iff int64
  __syncthreads();
  if (threadIdx.x == 0) flag[0] = (cnt > 200) ? 1 : 0;
  for (int i = threadIdx.x; i < NB; i += 256) gcur[i] = i * BCAP2;
}

// ---------------- LDS-binning multisplit: edges -> bucket-contiguous staged ----------------
__global__ __launch_bounds__(1024) void k_bin(const void* __restrict__ ei, const int* __restrict__ flag,
                                              int* __restrict__ gcur, int* __restrict__ staged){
  __shared__ int hcnt[256];
  __shared__ int pref[256];
  __shared__ int bnd[200];
  __shared__ int hrun[196];
  __shared__ int gb[196];
  __shared__ int sbuf[RND];
  int t = threadIdx.x;
  int base = blockIdx.x * RND;
  bool f64 = (flag[0] != 0);
  int pay[4], bkt[4];
  #pragma unroll
  for (int k = 0; k < 4; ++k){
    int e = base + k * 1024 + t;
    if (e < NE){
      int src, dst;
      if (f64){ src = (int)((const long long*)ei)[e]; dst = (int)((const long long*)ei)[NE + e]; }
      else    { src = ((const int*)ei)[e];            dst = ((const int*)ei)[NE + e]; }
      pay[k] = (src << 9) | (dst & 511);
      bkt[k] = dst >> 9;
    } else { pay[k] = 0; bkt[k] = -1; }
  }
  if (t < 256) hcnt[t] = 0;
  __syncthreads();
  #pragma unroll
  for (int k = 0; k < 4; ++k)
    if (bkt[k] >= 0) atomicAdd(&hcnt[bkt[k]], 1);
  __syncthreads();
  if (t < 256) pref[t] = hcnt[t];
  __syncthreads();
  for (int off = 1; off < 256; off <<= 1){
    int v = 0;
    if (t < 256 && t >= off) v = pref[t - off];
    __syncthreads();
    if (t < 256) pref[t] += v;
    __syncthreads();
  }
  if (t < 196){
    int excl = pref[t] - hcnt[t];
    bnd[t] = excl;
    hrun[t] = excl;
    gb[t] = (hcnt[t] > 0) ? atomicAdd(&gcur[t], hcnt[t]) : 0;
  }
  if (t == 196) bnd[196] = 0;
  __syncthreads();
  if (t == 0) bnd[196] = pref[255];
  __syncthreads();
  #pragma unroll
  for (int k = 0; k < 4; ++k)
    if (bkt[k] >= 0){
      int lp = atomicAdd(&hrun[bkt[k]], 1);
      sbuf[lp] = pay[k];
    }
  __syncthreads();
  int total = bnd[196];
  for (int i = t; i < total; i += 1024){
    int b = 0;
    #pragma unroll
    for (int sh = 128; sh > 0; sh >>= 1)
      if (b + sh <= 196 && bnd[b + sh] <= i) b += sh;
    staged[gb[b] + (i - bnd[b])] = sbuf[i];
  }
}

// ---------------- per-bucket degree count (LDS atomics only) ----------------
__global__ __launch_bounds__(256) void k_bdeg(const int* __restrict__ staged, const int* __restrict__ gcur,
                                              int* __restrict__ deg){
  __shared__ int dcnt[512];
  int b = blockIdx.x, t = threadIdx.x;
  for (int l = t; l < 512; l += 256) dcnt[l] = 0;
  __syncthreads();
  int cnt = min(gcur[b] - b * BCAP2, BCAP2);
  const int* sp = staged + b * BCAP2;
  for (int i = t; i < cnt; i += 256)
    atomicAdd(&dcnt[sp[i] & 511], 1);
  __syncthreads();
  for (int l = t; l < 512; l += 256){
    int n = b * 512 + l;
    if (n < NN) deg[n] = dcnt[l];
  }
}

// ---------------- scans ----------------
__global__ void k_scan1(const int* __restrict__ deg, int* __restrict__ cinc, int* __restrict__ part){
  __shared__ int b[1024];
  int i = blockIdx.x * 1024 + threadIdx.x;
  int v = (i < NN) ? deg[i] : 0;
  b[threadIdx.x] = v; __syncthreads();
  for (int off = 1; off < 1024; off <<= 1){
    int t = (threadIdx.x >= off) ? b[threadIdx.x - off] : 0;
    __syncthreads();
    b[threadIdx.x] += t;
    __syncthreads();
  }
  if (i < NN) cinc[i] = b[threadIdx.x];
  if (threadIdx.x == 1023) part[blockIdx.x] = b[1023];
}

__global__ void k_scan2(int* __restrict__ part, int nchunk){
  __shared__ int b[128];
  int tid = threadIdx.x;
  int v = (tid < nchunk) ? part[tid] : 0;
  b[tid] = v; __syncthreads();
  for (int off = 1; off < 128; off <<= 1){
    int t = (tid >= off) ? b[tid - off] : 0;
    __syncthreads();
    b[tid] += t;
    __syncthreads();
  }
  if (tid < nchunk) part[tid] = b[tid] - v;   // exclusive
}

__global__ void k_scan3(const int* __restrict__ deg, const int* __restrict__ cinc,
                        const int* __restrict__ part, int* __restrict__ rowp){
  int i = blockIdx.x * 1024 + threadIdx.x;
  if (i < NN){
    rowp[i] = cinc[i] - deg[i] + part[blockIdx.x];
  }
  if (i == 0) rowp[NN] = NE;
}

// ---------------- per-bucket scatter into CSR ----------------
__global__ __launch_bounds__(256) void k_scatter2(const int* __restrict__ staged, const int* __restrict__ gcur,
                                                  const int* __restrict__ rowp, int* __restrict__ colidx){
  __shared__ int cur[512];
  int b = blockIdx.x, t = threadIdx.x;
  for (int l = t; l < 512; l += 256){
    int n = b * 512 + l;
    cur[l] = (n < NN) ? rowp[n] : 0;
  }
  __syncthreads();
  int cnt = min(gcur[b] - b * BCAP2, BCAP2);
  const int* sp = staged + b * BCAP2;
  for (int i = t; i < cnt; i += 256){
    int p = sp[i];
    int pos = atomicAdd(&cur[p & 511], 1);
    colidx[pos] = p >> 9;
  }
}

// ---------------- prep stage 1 ----------------
__global__ void k_prep_sort(const float* __restrict__ w1, const float* __restrict__ b1,
                            const float* __restrict__ g1, const float* __restrict__ be1,
                            const float* __restrict__ m1, const float* __restrict__ v1,
                            const float* __restrict__ w3, const float* __restrict__ b3,
                            const float* __restrict__ g2, const float* __restrict__ be2,
                            const float* __restrict__ m2, const float* __restrict__ v2,
                            float* __restrict__ aC, float* __restrict__ cC,
                            float* __restrict__ thrS, int* __restrict__ pos,
                            unsigned short* __restrict__ w3s, float* __restrict__ b3p){
  __shared__ float key[256];
  __shared__ int idx[256];
  int tid = threadIdx.x;
  {
    float inv = rsqrtf(v1[tid] + EPS);
    float sc = g1[tid] * inv;
    float a = w1[tid] * sc;
    float c = (b1[tid] - m1[tid]) * sc + be1[tid];
    aC[tid] = a; cC[tid] = c;
    key[tid] = (a != 0.0f) ? (-c / a) : __int_as_float(0x7f800000);
    idx[tid] = tid;
  }
  __syncthreads();
  for (int k = 2; k <= 256; k <<= 1){
    for (int j = k >> 1; j > 0; j >>= 1){
      int ixj = tid ^ j;
      if (ixj > tid){
        float k1 = key[tid], k2 = key[ixj];
        bool asc = ((tid & k) == 0);
        if ((k1 > k2) == asc){
          int i1 = idx[tid];
          key[tid] = k2; key[ixj] = k1;
          idx[tid] = idx[ixj]; idx[ixj] = i1;
        }
      }
      __syncthreads();
    }
  }
  thrS[tid] = key[tid];
  pos[idx[tid]] = tid;
  if (tid < 64){
    float i2 = rsqrtf(v2[tid] + EPS);
    b3p[tid] = (b3[tid] - m2[tid]) * i2 * g2[tid] + be2[tid];
  }
  for (int id = tid; id < 8192; id += 256){
    int cs = id >> 11, r = id & 2047;
    int kt = r >> 9;  r &= 511;
    int l = r >> 3;   int mi = r & 7;
    int krow = kt * 32 + (l >> 4) * 8 + mi;
    int col  = cs * 16 + (l & 15);
    float i2 = rsqrtf(v2[col] + EPS);
    w3s[id] = f2b(w3[krow * 64 + col] * i2 * g2[col]);
  }
}

// ---------------- prep stage 2: interleaved row layout ----------------
// Row t (512 B) = 32 x uint4: quad fq -> shorts [fq*8 .. fq*8+3] = A feats 4fq..4fq+3,
// shorts [fq*8+4 .. fq*8+7] = B feats 4fq..4fq+3.  One ds_read_b128 per lane in k_agg.
__global__ void k_tab(const float* __restrict__ aC, const float* __restrict__ cC,
                      const int* __restrict__ pos, const float* __restrict__ w2,
                      const float* __restrict__ b2, unsigned short* __restrict__ tabG){
  __shared__ float ca[256], cc[256];
  int t = blockIdx.x;
  int tid = threadIdx.x;
  {
    float a = aC[tid], c = cC[tid];
    int p = pos[tid];
    bool act = (a > 0.f) ? (p < t) : ((a < 0.f) ? (p >= t) : (c > 0.f));
    ca[tid] = act ? a : 0.f;
    cc[tid] = act ? c : 0.f;
  }
  __syncthreads();
  int f = tid & 127, sel = tid >> 7;
  const float* coef = sel ? cc : ca;
  float acc = sel ? b2[f] : 0.f;
  #pragma unroll 8
  for (int j = 0; j < 256; ++j)
    acc = fmaf(coef[j], w2[j * 128 + f], acc);
  int fq = f >> 2, e = f & 3;
  tabG[t * 256 + fq * 8 + sel * 4 + e] = f2b(acc);
}

// ---------------- wb -> bf16 MFMA B-fragment order ----------------
__global__ void k_wbS(const float* __restrict__ wb, unsigned short* __restrict__ wbS){
  int id = blockIdx.x * 256 + threadIdx.x;
  if (id >= 64 * 6144) return;
  int j = id / 6144;
  int r = id % 6144;
  int f = r >> 9;  r &= 511;
  int l = r >> 3;  int mi = r & 7;
  int kt = f / 6, cs = f % 6;
  int i = kt * 32 + (l >> 4) * 8 + mi;
  int k = cs * 16 + (l & 15);
  wbS[id] = f2b(wb[(k * 64 + i) * 64 + j]);
}

// ---------------- scalar aggregation + interval search ----------------
__global__ void k_sagg(const float* __restrict__ x, const int* __restrict__ rowp,
                       const int* __restrict__ colidx, const float* __restrict__ thrS,
                       float4* __restrict__ info){
  __shared__ float thr[256];
  thr[threadIdx.x] = thrS[threadIdx.x];
  __syncthreads();
  int n = blockIdx.x * 256 + threadIdx.x;
  if (n >= NN) return;
  float2 xv = ((const float2*)x)[n];
  float sA = xv.y, sB = xv.x;
  int s0 = rowp[n], s1 = rowp[n + 1];
  for (int e = s0; e < s1; ++e){
    int j = colidx[e];
    float2 xj = ((const float2*)x)[j];
    sA += xj.y; sB += xj.x;
  }
  int tA = 0, tB = 0;
  #pragma unroll
  for (int sh = 128; sh > 0; sh >>= 1){
    if (tA + sh <= 256 && thr[tA + sh - 1] < sA) tA += sh;
    if (tB + sh <= 256 && thr[tB + sh - 1] < sB) tB += sh;
  }
  info[n] = make_float4(sA, sB, __uint_as_float((unsigned)tA | ((unsigned)tB << 16)), 0.f);
}

// ---------------- heavy aggregation via LDS table (interleaved rows: 1 b128/lane/edge) ----------------
__global__ __launch_bounds__(1024) void k_agg(
    const float4* __restrict__ info, const int* __restrict__ rowp,
    const int* __restrict__ colidx, const unsigned short* __restrict__ tabG,
    unsigned short* __restrict__ mA, unsigned short* __restrict__ mB){
  extern __shared__ unsigned tab32[];
  for (int i = threadIdx.x; i < 257 * 128; i += 1024)
    tab32[i] = ((const unsigned*)tabG)[i];
  __syncthreads();
  int lane = threadIdx.x & 63;
  int wv = (blockIdx.x * 1024 + threadIdx.x) >> 6;
  int nw = (gridDim.x * 1024) >> 6;
  int p  = lane >> 5;
  int fq = lane & 31;
  int foff = fq << 4;          // byte offset of this lane's uint4 within the 512-B row

  int n = wv;
  if (n >= NN) return;
  int s0 = rowp[n], s1 = rowp[n + 1];
  float4 inf;
  {
    int cnt = s1 - s0 + 1;
    inf = make_float4(0, 0, 0, 0);
    if (lane < cnt) inf = info[(lane == 0) ? n : colidx[s0 + lane - 1]];
  }
  while (true){
    int cnt = s1 - s0 + 1;
    int nnx = n + nw;
    float4 infc = inf;           // this node's chunk-0 gather (already in flight/complete)
    int s0c = s0;
    int ns0 = 0, ns1 = 0;
    if (nnx < NN){
      ns0 = rowp[nnx]; ns1 = rowp[nnx + 1];
      int ncnt = ns1 - ns0 + 1;
      inf = make_float4(0, 0, 0, 0);
      if (lane < ncnt) inf = info[(lane == 0) ? nnx : colidx[ns0 + lane - 1]];
    }
    float a0 = 0.f, a1 = 0.f, a2 = 0.f, a3 = 0.f;
    for (int base = 0; base < cnt; base += 64){
      if (base > 0){
        infc = make_float4(0, 0, 0, 0);
        int nb = base + lane;
        if (nb < cnt) infc = info[colidx[s0c + nb - 1]];
      }
      int m = min(cnt - base, 64);
      for (int q = 0; q < m; ++q){
        float sA = __shfl(infc.x, q);
        float sB = __shfl(infc.y, q);
        unsigned tt = __float_as_uint(__shfl(infc.z, q));
        float s = p ? sB : sA;
        int   t = p ? (int)(tt >> 16) : (int)(tt & 0xffffu);
        const char* rp = (const char*)tab32 + t * 512;
        uint4 v = *(const uint4*)(rp + foff);       // [A0A1 A2A3 B0B1 B2B3]
        a0 += fmaf(s, b2f_lo(v.x), b2f_lo(v.z));
        a1 += fmaf(s, b2f_hi(v.x), b2f_hi(v.z));
        a2 += fmaf(s, b2f_lo(v.y), b2f_lo(v.w));
        a3 += fmaf(s, b2f_hi(v.y), b2f_hi(v.w));
      }
    }
    unsigned short* dst = (p ? mB : mA) + (size_t)n * 128 + fq * 4;
    unsigned o0 = (unsigned)f2b(a0) | ((unsigned)f2b(a1) << 16);
    unsigned o1 = (unsigned)f2b(a2) | ((unsigned)f2b(a3) << 16);
    *((uint2*)dst) = make_uint2(o0, o1);
    if (nnx >= NN) break;
    n = nnx; s0 = ns0; s1 = ns1;
  }
}

// ---------------- mlp2 (MFMA) ----------------
__global__ void k_mlp2(const unsigned short* __restrict__ mA, const unsigned short* __restrict__ mB,
                       const unsigned short* __restrict__ w3s, const float* __restrict__ b3p,
                       unsigned short* __restrict__ h1, unsigned short* __restrict__ h2T){
  int lane = threadIdx.x & 63;
  int tile = (blockIdx.x * blockDim.x + threadIdx.x) >> 6;
  const int NT = 2 * NN / 16;
  if (tile >= NT) return;
  bool pB = (tile >= NN / 16);
  const unsigned short* src = pB ? (mB + (size_t)(tile - NN / 16) * 16 * 128)
                                 : (mA + (size_t)tile * 16 * 128);
  short8 afr[4];
  {
    int row = lane & 15, ko = (lane >> 4) * 8;
    #pragma unroll
    for (int kt = 0; kt < 4; ++kt)
      afr[kt] = *(const short8*)(src + row * 128 + kt * 32 + ko);
  }
  f32x4 acc[4];
  #pragma unroll
  for (int cs = 0; cs < 4; ++cs){
    f32x4 a = {0.f, 0.f, 0.f, 0.f};
    #pragma unroll
    for (int kt = 0; kt < 4; ++kt){
      short8 b = *(const short8*)(w3s + ((cs * 4 + kt) * 64 + lane) * 8);
      a = __builtin_amdgcn_mfma_f32_16x16x32_bf16(afr[kt], b, a, 0, 0, 0);
    }
    acc[cs] = a;
  }
  int col0 = lane & 15, r0 = (lane >> 4) * 4;
  if (!pB){
    int nb = tile * 16;
    #pragma unroll
    for (int cs = 0; cs < 4; ++cs){
      float bias = b3p[cs * 16 + col0];
      #pragma unroll
      for (int r = 0; r < 4; ++r){
        float v = fmaxf(acc[cs][r] + bias, 0.f);
        h1[(size_t)(nb + r0 + r) * 64 + cs * 16 + col0] = f2b(v);
      }
    }
  } else {
    int nb = (tile - NN / 16) * 16;
    #pragma unroll
    for (int cs = 0; cs < 4; ++cs){
      float bias = b3p[cs * 16 + col0];
      unsigned p0 = (unsigned)f2b(fmaxf(acc[cs][0] + bias, 0.f)) | ((unsigned)f2b(fmaxf(acc[cs][1] + bias, 0.f)) << 16);
      unsigned p1 = (unsigned)f2b(fmaxf(acc[cs][2] + bias, 0.f)) | ((unsigned)f2b(fmaxf(acc[cs][3] + bias, 0.f)) << 16);
      *(uint2*)(h2T + (size_t)(cs * 16 + col0) * NN + nb + r0) = make_uint2(p0, p1);
    }
  }
}

// ---------------- bilinear (96x64x64) + head + log_softmax ----------------
// R8 structure (2 waves, j-split, 64 rows), 12.25KB overlaid LDS, launch_bounds(128,2) (no spill).
__global__ __launch_bounds__(128, 2) void k_bil(
    const unsigned short* __restrict__ h1, const unsigned short* __restrict__ h2T,
    const unsigned short* __restrict__ wbS, const float* __restrict__ bbv,
    const float* __restrict__ w5, const float* __restrict__ b5,
    const float* __restrict__ w6, const float* __restrict__ b6,
    float* __restrict__ out){
  __shared__ float smem[3136];                 // 12544 B, all phases overlaid
  unsigned short* h2sT = (unsigned short*)smem;  // [64 j][64]: j*64 + rl*4 + rt
  int tid = threadIdx.x;
  int lane = tid & 63;
  int wv = tid >> 6;                           // 0 or 1
  int nb = blockIdx.x * 64;
  int rl = lane & 15, ko = (lane >> 4) * 8;
  for (int i = tid; i < 64 * 64; i += 128){
    int j = i >> 6, l = (i >> 2) & 15, rt = i & 3;
    int n = nb + rt * 16 + l;
    h2sT[i] = (n < NN) ? h2T[(size_t)j * NN + n] : (unsigned short)0;
  }
  float af[4][2][8];
  #pragma unroll
  for (int rt = 0; rt < 4; ++rt){
    int row = nb + rt * 16 + rl;
    #pragma unroll
    for (int kt = 0; kt < 2; ++kt){
      if (row < NN){
        uint4 rv = *(const uint4*)(h1 + (size_t)row * 64 + kt * 32 + ko);
        af[rt][kt][0] = b2f_lo(rv.x); af[rt][kt][1] = b2f_hi(rv.x);
        af[rt][kt][2] = b2f_lo(rv.y); af[rt][kt][3] = b2f_hi(rv.y);
        af[rt][kt][4] = b2f_lo(rv.z); af[rt][kt][5] = b2f_hi(rv.z);
        af[rt][kt][6] = b2f_lo(rv.w); af[rt][kt][7] = b2f_hi(rv.w);
      } else {
        #pragma unroll
        for (int e = 0; e < 8; ++e) af[rt][kt][e] = 0.f;
      }
    }
  }
  __syncthreads();
  f32x4 acc[4][6];
  #pragma unroll
  for (int rt = 0; rt < 4; ++rt)
    #pragma unroll
    for (int cs = 0; cs < 6; ++cs)
      acc[rt][cs] = (f32x4){0.f, 0.f, 0.f, 0.f};
  const unsigned short* wp = wbS + (size_t)lane * 8;
  int j0 = wv * 32, j1 = j0 + 32;
  for (int j = j0; j < j1; ++j){
    uint4 bf[2][6];
    #pragma unroll
    for (int kt = 0; kt < 2; ++kt)
      #pragma unroll
      for (int cs = 0; cs < 6; ++cs)
        bf[kt][cs] = *(const uint4*)(wp + (size_t)(j * 12 + kt * 6 + cs) * 512);
    uint2 hsv = *(const uint2*)(h2sT + j * 64 + rl * 4);
    float hsr[4];
    hsr[0] = b2f_lo(hsv.x); hsr[1] = b2f_hi(hsv.x);
    hsr[2] = b2f_lo(hsv.y); hsr[3] = b2f_hi(hsv.y);
    #pragma unroll
    for (int rt = 0; rt < 4; ++rt){
      float hs = hsr[rt];
      short8 a0, a1;
      #pragma unroll
      for (int e = 0; e < 8; ++e){
        a0[e] = (short)f2b(af[rt][0][e] * hs);
        a1[e] = (short)f2b(af[rt][1][e] * hs);
      }
      #pragma unroll
      for (int cs = 0; cs < 6; ++cs){
        acc[rt][cs] = __builtin_amdgcn_mfma_f32_16x16x32_bf16(a0, __builtin_bit_cast(short8, bf[0][cs]), acc[rt][cs], 0, 0, 0);
        acc[rt][cs] = __builtin_amdgcn_mfma_f32_16x16x32_bf16(a1, __builtin_bit_cast(short8, bf[1][cs]), acc[rt][cs], 0, 0, 0);
      }
    }
  }
  float* red = smem;
  __syncthreads();
  if (wv == 1){
    #pragma unroll
    for (int rt = 0; rt < 4; ++rt)
      #pragma unroll
      for (int cs = 0; cs < 3; ++cs){
        int col = cs * 16 + rl;
        #pragma unroll
        for (int r = 0; r < 4; ++r){
          int row = rt * 16 + (lane >> 4) * 4 + r;
          red[row * 49 + col] = acc[rt][cs][r];
        }
      }
  }
  __syncthreads();
  if (wv == 0){
    #pragma unroll
    for (int rt = 0; rt < 4; ++rt)
      #pragma unroll
      for (int cs = 0; cs < 3; ++cs){
        int col = cs * 16 + rl;
        #pragma unroll
        for (int r = 0; r < 4; ++r){
          int row = rt * 16 + (lane >> 4) * 4 + r;
          acc[rt][cs][r] += red[row * 49 + col];
        }
      }
  }
  __syncthreads();
  if (wv == 1){
    #pragma unroll
    for (int rt = 0; rt < 4; ++rt)
      #pragma unroll
      for (int cs = 3; cs < 6; ++cs){
        int col = (cs - 3) * 16 + rl;
        #pragma unroll
        for (int r = 0; r < 4; ++r){
          int row = rt * 16 + (lane >> 4) * 4 + r;
          red[row * 49 + col] = acc[rt][cs][r];
        }
      }
  }
  __syncthreads();
  if (wv == 0){
    #pragma unroll
    for (int rt = 0; rt < 4; ++rt)
      #pragma unroll
      for (int cs = 3; cs < 6; ++cs){
        int col = (cs - 3) * 16 + rl;
        #pragma unroll
        for (int r = 0; r < 4; ++r){
          int row = rt * 16 + (lane >> 4) * 4 + r;
          acc[rt][cs][r] += red[row * 49 + col];
        }
      }
  }
  __syncthreads();
  if (wv == 0){
    unsigned short* hbs = (unsigned short*)smem;   // [64][98]
    #pragma unroll
    for (int rt = 0; rt < 4; ++rt)
      #pragma unroll
      for (int cs = 0; cs < 6; ++cs){
        int col = cs * 16 + rl;
        float bias = bbv[col];
        #pragma unroll
        for (int r = 0; r < 4; ++r){
          int rowl = rt * 16 + (lane >> 4) * 4 + r;
          hbs[rowl * 98 + col] = f2b(acc[rt][cs][r] + bias);
        }
      }
    int n = nb + lane;
    if (n < NN){
      float u[6];
      #pragma unroll
      for (int q = 0; q < 6; ++q) u[q] = b5[q];
      for (int jj = 0; jj < 96; ++jj){
        float hv = b2f_u(hbs[lane * 98 + jj]);
        #pragma unroll
        for (int q = 0; q < 6; ++q) u[q] = fmaf(hv, w5[jj * 6 + q], u[q]);
      }
      #pragma unroll
      for (int q = 0; q < 6; ++q) u[q] = fmaxf(u[q], 0.f);
      float v[6];
      #pragma unroll
      for (int q = 0; q < 6; ++q){
        float a2 = b6[q];
        #pragma unroll
        for (int pp = 0; pp < 6; ++pp) a2 = fmaf(u[pp], w6[pp * 6 + q], a2);
        v[q] = a2;
      }
      float mx = v[0];
      #pragma unroll
      for (int q = 1; q < 6; ++q) mx = fmaxf(mx, v[q]);
      float se = 0.f;
      #pragma unroll
      for (int q = 0; q < 6; ++q) se += expf(v[q] - mx);
      float ls = logf(se);
      #pragma unroll
      for (int q = 0; q < 6; ++q) out[(size_t)n * 6 + q] = v[q] - mx - ls;
    }
  }
}

extern "C" void kernel_launch(void* const* d_in, const int* in_sizes, int n_in,
                              void* d_out, int out_size, void* d_ws, size_t ws_size,
                              hipStream_t stream){
  const float* x   = (const float*)d_in[0];
  const void*  ei  = d_in[1];
  const float* w1  = (const float*)d_in[2];
  const float* b1  = (const float*)d_in[3];
  const float* g1  = (const float*)d_in[4];
  const float* be1 = (const float*)d_in[5];
  const float* m1  = (const float*)d_in[6];
  const float* v1  = (const float*)d_in[7];
  const float* w2  = (const float*)d_in[8];
  const float* b2  = (const float*)d_in[9];
  const float* w3  = (const float*)d_in[10];
  const float* b3  = (const float*)d_in[11];
  const float* g2  = (const float*)d_in[12];
  const float* be2 = (const float*)d_in[13];
  const float* m2  = (const float*)d_in[14];
  const float* v2  = (const float*)d_in[15];
  const float* wb  = (const float*)d_in[16];
  const float* bb  = (const float*)d_in[17];
  const float* w5  = (const float*)d_in[18];
  const float* b5  = (const float*)d_in[19];
  const float* w6  = (const float*)d_in[20];
  const float* b6  = (const float*)d_in[21];
  float* out = (float*)d_out;

  char* ws = (char*)d_ws;
  size_t off = 0;
  auto alloc = [&](size_t bytes) -> void* {
    void* p = ws + off;
    off += (bytes + 255) & ~(size_t)255;
    return p;
  };
  int* deg      = (int*)alloc((size_t)NN * 4);
  int* rowp     = (int*)alloc((size_t)(NN + 1) * 4);
  int* cinc     = (int*)alloc((size_t)NN * 4);
  int* part     = (int*)alloc(1024 * 4);
  int* flag     = (int*)alloc(256);
  int* gcur     = (int*)alloc((size_t)NB * 4 + 256);
  int* colidx   = (int*)alloc((size_t)NE * 4);
  float4* info  = (float4*)alloc((size_t)NN * 16);
  unsigned short* tabG = (unsigned short*)alloc(257 * 256 * 2);
  float* thrS   = (float*)alloc(256 * 4);
  float* aC     = (float*)alloc(256 * 4);
  float* cC     = (float*)alloc(256 * 4);
  int* pos      = (int*)alloc(256 * 4);
  unsigned short* w3s  = (unsigned short*)alloc(8192 * 2);
  float* b3p    = (float*)alloc(64 * 4);
  unsigned short* wbS  = (unsigned short*)alloc((size_t)393216 * 2);
  unsigned short* mA   = (unsigned short*)alloc((size_t)NN * 128 * 2);
  unsigned short* mB   = (unsigned short*)alloc((size_t)NN * 128 * 2);
  unsigned short* h1   = (unsigned short*)alloc((size_t)NN * 64 * 2);
  unsigned short* h2T  = (unsigned short*)alloc((size_t)NN * 64 * 2);
  int* staged   = (int*)mA;   // 8.03 MB aliases mA; consumed before k_agg writes mA

  k_probe<<<1, 256, 0, stream>>>((const int*)ei, flag, gcur);
  k_bin<<<NRND, 1024, 0, stream>>>(ei, flag, gcur, staged);
  k_bdeg<<<NB, 256, 0, stream>>>(staged, gcur, deg);
  k_scan1<<<NCHUNK, 1024, 0, stream>>>(deg, cinc, part);
  k_scan2<<<1, 128, 0, stream>>>(part, NCHUNK);
  k_scan3<<<NCHUNK, 1024, 0, stream>>>(deg, cinc, part, rowp);
  k_scatter2<<<NB, 256, 0, stream>>>(staged, gcur, rowp, colidx);
  k_prep_sort<<<1, 256, 0, stream>>>(w1, b1, g1, be1, m1, v1, w3, b3, g2, be2, m2, v2,
                                     aC, cC, thrS, pos, w3s, b3p);
  k_tab<<<257, 256, 0, stream>>>(aC, cC, pos, w2, b2, tabG);
  k_wbS<<<(64 * 6144 + 255) / 256, 256, 0, stream>>>(wb, wbS);
  k_sagg<<<(NN + 255) / 256, 256, 0, stream>>>(x, rowp, colidx, thrS, info);
  hipFuncSetAttribute((const void*)k_agg, hipFuncAttributeMaxDynamicSharedMemorySize, 257 * 128 * 4);
  k_agg<<<256, 1024, 257 * 128 * 4, stream>>>(info, rowp, colidx, tabG, mA, mB);
  k_mlp2<<<(2 * NN / 16 + 3) / 4, 256, 0, stream>>>(mA, mB, w3s, b3p, h1, h2T);
  k_bil<<<(NN + 63) / 64, 128, 0, stream>>>(h1, h2T, wbS, bb, w5, b5, w6, b6, out);
}